// Round 6
// baseline (257.119 us; speedup 1.0000x reference)
//
#include <hip/hip_runtime.h>
#include <hip/hip_bf16.h>
#include <math.h>

#define LEN 128
#define NCELLS 8256          // LEN*(LEN+1)/2
#define TOTAL 349504         // sum_{l=1}^{127} (128-l)*l
#define NCONSTR 8
#define BONUS 1000.0f
#define NT 512

// Barrier WITHOUT vmcnt drain: only LDS writes must be ordered; register
// prefetch loads stay in flight across the barrier (T4 discipline).
__device__ __forceinline__ void level_barrier() {
    __builtin_amdgcn_sched_barrier(0);
    asm volatile("s_waitcnt lgkmcnt(0)\n\ts_barrier" ::: "memory");
    __builtin_amdgcn_sched_barrier(0);
}

// DPP quad_perm cross-lane max (VALU pipe, no LDS traffic).
__device__ __forceinline__ float dpp_xor1_max(float v) {
    int r = __builtin_amdgcn_update_dpp(0, __float_as_int(v), 0xB1, 0xF, 0xF, true);
    return fmaxf(v, __int_as_float(r));
}
__device__ __forceinline__ float dpp_xor2_max(float v) {
    int r = __builtin_amdgcn_update_dpp(0, __float_as_int(v), 0x4E, 0xF, 0xF, true);
    return fmaxf(v, __int_as_float(r));
}

template<int LG>
__device__ __forceinline__ void redmax(float& a) {
    #pragma unroll
    for (int mm = (1 << LG) >> 1; mm >= 4; mm >>= 1)
        a = fmaxf(a, __shfl_xor(a, mm));
    if constexpr (LG >= 2) a = dpp_xor2_max(a);
    if constexpr (LG >= 1) a = dpp_xor1_max(a);
}

// One CKY level over a SINGLE chart (pred or constr; block-level split).
// Phase 1: issue all 2*JM independent ds_read_b32 into register arrays;
// phase 2: consume. Prefetch loads level+1 scores into rnxt (in flight
// across the barrier).
template<int LG, int LG2, int JM, int JM2>
__device__ __forceinline__ void lstep(const int level, int& soff,
        const float* __restrict__ g, float* __restrict__ chart,
        float (&rcur)[16], float (&rnxt)[16], const int tid)
{
    const int N = level;
    const int L = LEN - level;
    constexpr int T = 1 << LG;
    const int pos = tid >> LG;
    const int sub = tid & (T - 1);
    const int soff_n = soff + L * N;

    // ---- issue next level's score loads (consumed after next barrier) ----
    if constexpr (LG2 >= 0) {
        constexpr int T2 = 1 << LG2;
        const int N2 = level + 1;
        const int L2 = L - 1;
        const int pos2 = tid >> LG2;
        const int sub2 = tid & (T2 - 1);
        if (pos2 < L2) {
            const float* __restrict__ gp = g + soff_n + pos2 * N2 + sub2;
            #pragma unroll
            for (int j = 0; j < JM2; j++) {
                if (sub2 + j * T2 < N2) rnxt[j] = gp[j * T2];
            }
        }
    }

    // ---- compute this level ----
    float bp = -INFINITY;
    if (pos < L) {
        const int jml = (N - sub + T - 1) >> LG;   // per-lane valid trip count
        float lv[JM], rv[JM], xs[JM];
        #pragma unroll
        for (int j = 0; j < JM; j++) {
            const int n = sub + j * T;
            const int m = level - 1 - n;
            const bool v = (j < jml);
            const int l_idx = ((n * (257 - n)) >> 1) + pos;
            int r_idx = ((m * (257 - m)) >> 1) + pos + n + 1;
            r_idx = v ? r_idx : 0;
            lv[j] = chart[l_idx];
            rv[j] = chart[r_idx];
            xs[j] = v ? rcur[j] : -INFINITY;
        }
        #pragma unroll
        for (int j = 0; j < JM; j++)
            bp = fmaxf(bp, lv[j] + rv[j] + xs[j]);
    }
    redmax<LG>(bp);
    if (pos < L && sub == 0)
        chart[((level * (257 - level)) >> 1) + pos] += bp;
    level_barrier();
    soff = soff_n;
}

// 4 levels at TPP=4, JM=K exactly (levels 4K-3..4K), double-buffered.
template<int K>
__device__ __forceinline__ void seg4(int& soff, const float* __restrict__ g,
        float* __restrict__ chart, float (&rA)[16], float (&rB)[16], const int tid)
{
    const int l0 = 4 * K - 3;
    #pragma unroll 1
    for (int l = l0; l < l0 + 4; l += 2) {
        lstep<2, 2, K, K + 1>(l,     soff, g, chart, rA, rB, tid);
        lstep<2, 2, K, K + 1>(l + 1, soff, g, chart, rB, rA, tid);
    }
}

__global__ __launch_bounds__(NT)
void cky_kernel(const float* __restrict__ scores,
                const int* __restrict__ cpos,
                float* __restrict__ roots)
{
    __shared__ float chart[NCELLS];    // one chart (pred OR constr)

    const int bb   = blockIdx.x;
    const int b    = bb & 255;         // batch element
    const int kind = bb >> 8;          // 0 = pred, 1 = constr (b, b+256 same XCD)
    const int tid  = threadIdx.x;
    const float* __restrict__ g = scores + (size_t)b * TOTAL;

    float rA[16], rB[16];

    // ---- prefetch level 1 scores (N=1, TPP=4 mapping) ----
    {
        const int pos = tid >> 2;
        const int sub = tid & 3;
        if (pos < 127 && sub == 0) rA[0] = g[pos];
    }
    int cp = 0;
    if (tid < NCONSTR) cp = cpos[b * NCONSTR + tid];

    // ---- init chart ----
    for (int i = tid; i < NCELLS; i += NT) chart[i] = 0.f;
    level_barrier();
    if (kind && tid < NCONSTR) chart[cp] = BONUS;  // set; duplicates benign
    level_barrier();

    int soff = 0;

    // ---- TPP=4: levels 1..60 via exact-JM segments ----
    seg4<1>(soff, g, chart, rA, rB, tid);
    seg4<2>(soff, g, chart, rA, rB, tid);
    seg4<3>(soff, g, chart, rA, rB, tid);
    seg4<4>(soff, g, chart, rA, rB, tid);
    seg4<5>(soff, g, chart, rA, rB, tid);
    seg4<6>(soff, g, chart, rA, rB, tid);
    seg4<7>(soff, g, chart, rA, rB, tid);
    seg4<8>(soff, g, chart, rA, rB, tid);
    seg4<9>(soff, g, chart, rA, rB, tid);
    seg4<10>(soff, g, chart, rA, rB, tid);
    seg4<11>(soff, g, chart, rA, rB, tid);
    seg4<12>(soff, g, chart, rA, rB, tid);
    seg4<13>(soff, g, chart, rA, rB, tid);
    seg4<14>(soff, g, chart, rA, rB, tid);
    seg4<15>(soff, g, chart, rA, rB, tid);
    // ---- TPP=4 tail: levels 61..63 ----
    lstep<2,2,16,16>(61, soff, g, chart, rA, rB, tid);
    lstep<2,2,16,16>(62, soff, g, chart, rB, rA, tid);
    lstep<2,3,16,8> (63, soff, g, chart, rA, rB, tid);   // next TPP=8
    // ---- TPP=8: levels 64..95 ----
    lstep<3,3,8,9>  (64, soff, g, chart, rB, rA, tid);
    #pragma unroll 1
    for (int l = 65; l < 72; l += 2) {                   // 65..72 (JM=9)
        lstep<3,3,9,10>(l,     soff, g, chart, rA, rB, tid);
        lstep<3,3,9,10>(l + 1, soff, g, chart, rB, rA, tid);
    }
    #pragma unroll 1
    for (int l = 73; l < 80; l += 2) {                   // 73..80 (JM=10)
        lstep<3,3,10,11>(l,     soff, g, chart, rA, rB, tid);
        lstep<3,3,10,11>(l + 1, soff, g, chart, rB, rA, tid);
    }
    #pragma unroll 1
    for (int l = 81; l < 88; l += 2) {                   // 81..88 (JM=11)
        lstep<3,3,11,12>(l,     soff, g, chart, rA, rB, tid);
        lstep<3,3,11,12>(l + 1, soff, g, chart, rB, rA, tid);
    }
    #pragma unroll 1
    for (int l = 89; l < 94; l += 2) {                   // 89..94 (JM=12)
        lstep<3,3,12,12>(l,     soff, g, chart, rA, rB, tid);
        lstep<3,3,12,12>(l + 1, soff, g, chart, rB, rA, tid);
    }
    lstep<3,4,12,6> (95, soff, g, chart, rA, rB, tid);   // next TPP=16
    // ---- TPP=16: levels 96..111 ----
    lstep<4,4,6,7>  (96, soff, g, chart, rB, rA, tid);
    #pragma unroll 1
    for (int l = 97; l < 110; l += 2) {                  // 97..110 (JM=7)
        lstep<4,4,7,7>(l,     soff, g, chart, rA, rB, tid);
        lstep<4,4,7,7>(l + 1, soff, g, chart, rB, rA, tid);
    }
    lstep<4,5,7,4>(111, soff, g, chart, rA, rB, tid);    // next TPP=32
    // ---- TPP=32: levels 112..119 ----
    lstep<5,5,4,4>(112, soff, g, chart, rB, rA, tid);
    #pragma unroll 1
    for (int l = 113; l < 118; l += 2) {                 // 113..118
        lstep<5,5,4,4>(l,     soff, g, chart, rA, rB, tid);
        lstep<5,5,4,4>(l + 1, soff, g, chart, rB, rA, tid);
    }
    lstep<5,6,4,2>(119, soff, g, chart, rA, rB, tid);    // next TPP=64
    // ---- TPP=64: levels 120..127 ----
    lstep<6,6,2,2>(120, soff, g, chart, rB, rA, tid);
    #pragma unroll 1
    for (int l = 121; l < 126; l += 2) {                 // 121..126
        lstep<6,6,2,2>(l,     soff, g, chart, rA, rB, tid);
        lstep<6,6,2,2>(l + 1, soff, g, chart, rB, rA, tid);
    }
    lstep<6,-1,2,2>(127, soff, g, chart, rA, rB, tid);   // root; no prefetch

    // ---- publish this chart's root; all 512 slots written every call ----
    if (tid == 0) roots[bb] = chart[NCELLS - 1];
}

__global__ __launch_bounds__(256)
void final_kernel(const float* __restrict__ roots, float* __restrict__ out) {
    const int t = threadIdx.x;                 // 0..255 = batch element
    const float pred   = roots[t];
    const float constr = roots[256 + t] - BONUS * NCONSTR;
    const float diff   = pred - constr;
    const float mask   = (fabsf(diff) >= 0.001f) ? 1.f : 0.f;
    float h = fmaxf(1.0f + diff, 0.f) * mask;
    float m = mask;
    #pragma unroll
    for (int s = 32; s > 0; s >>= 1) {
        h += __shfl_xor(h, s);
        m += __shfl_xor(m, s);
    }
    __shared__ float sh[8];
    const int w = t >> 6;
    if ((t & 63) == 0) { sh[w] = h; sh[4 + w] = m; }
    __syncthreads();
    if (t == 0) {
        const float H = sh[0] + sh[1] + sh[2] + sh[3];
        const float M = sh[4] + sh[5] + sh[6] + sh[7];
        out[0] = (M > 0.1f) ? (H / fmaxf(M, 1.f)) : H;
    }
}

extern "C" void kernel_launch(void* const* d_in, const int* in_sizes, int n_in,
                              void* d_out, int out_size, void* d_ws, size_t ws_size,
                              hipStream_t stream) {
    const float* scores = (const float*)d_in[0];
    const int*   cpos   = (const int*)d_in[1];
    float* out   = (float*)d_out;
    float* roots = (float*)d_ws;               // 512 floats

    cky_kernel<<<dim3(512), dim3(NT), 0, stream>>>(scores, cpos, roots);
    final_kernel<<<dim3(1), dim3(256), 0, stream>>>(roots, out);
}

// Round 7
// 172.967 us; speedup vs baseline: 1.4865x; 1.4865x over previous
//
#include <hip/hip_runtime.h>
#include <hip/hip_bf16.h>
#include <math.h>

#define LEN 128
#define NCELLS_PAD 8384      // 8256 cells + pad for clamped/garbage-lane reads
#define TOTAL 349504         // sum_{l=1}^{127} (128-l)*l
#define NCONSTR 8
#define BONUS 1000.0f
#define NT 512
#define PMAX 7               // max pre-issued j's (lgkmcnt is 4-bit: 2*PMAX<=14)

__device__ __forceinline__ int OFFi(int n) { return (n * (257 - n)) >> 1; }

// Counted lgkmcnt wait (exact literal; gfx9 lgkmcnt field is 4 bits).
template<int N> __device__ __forceinline__ void wait_lgkm() {
    static_assert(N >= 0 && N <= 15, "lgkmcnt range");
    if constexpr (N == 0)  asm volatile("s_waitcnt lgkmcnt(0)" ::: "memory");
    else if constexpr (N == 1)  asm volatile("s_waitcnt lgkmcnt(1)" ::: "memory");
    else if constexpr (N == 2)  asm volatile("s_waitcnt lgkmcnt(2)" ::: "memory");
    else if constexpr (N == 3)  asm volatile("s_waitcnt lgkmcnt(3)" ::: "memory");
    else if constexpr (N == 4)  asm volatile("s_waitcnt lgkmcnt(4)" ::: "memory");
    else if constexpr (N == 5)  asm volatile("s_waitcnt lgkmcnt(5)" ::: "memory");
    else if constexpr (N == 6)  asm volatile("s_waitcnt lgkmcnt(6)" ::: "memory");
    else if constexpr (N == 7)  asm volatile("s_waitcnt lgkmcnt(7)" ::: "memory");
    else if constexpr (N == 8)  asm volatile("s_waitcnt lgkmcnt(8)" ::: "memory");
    else if constexpr (N == 9)  asm volatile("s_waitcnt lgkmcnt(9)" ::: "memory");
    else if constexpr (N == 10) asm volatile("s_waitcnt lgkmcnt(10)" ::: "memory");
    else if constexpr (N == 11) asm volatile("s_waitcnt lgkmcnt(11)" ::: "memory");
    else if constexpr (N == 12) asm volatile("s_waitcnt lgkmcnt(12)" ::: "memory");
    else if constexpr (N == 13) asm volatile("s_waitcnt lgkmcnt(13)" ::: "memory");
    else if constexpr (N == 14) asm volatile("s_waitcnt lgkmcnt(14)" ::: "memory");
    else                        asm volatile("s_waitcnt lgkmcnt(15)" ::: "memory");
}

// Barrier WITHOUT any counter drain (waits are done, counted, beforehand).
__device__ __forceinline__ void bar() {
    __builtin_amdgcn_sched_barrier(0);
    asm volatile("s_barrier" ::: "memory");
    __builtin_amdgcn_sched_barrier(0);
}

// DPP quad_perm cross-lane max (VALU pipe, no LDS traffic).
__device__ __forceinline__ float dpp_xor1_max(float v) {
    int r = __builtin_amdgcn_update_dpp(0, __float_as_int(v), 0xB1, 0xF, 0xF, true);
    return fmaxf(v, __int_as_float(r));
}
__device__ __forceinline__ float dpp_xor2_max(float v) {
    int r = __builtin_amdgcn_update_dpp(0, __float_as_int(v), 0x4E, 0xF, 0xF, true);
    return fmaxf(v, __int_as_float(r));
}
template<int LG>
__device__ __forceinline__ void redmax2(float& a, float& b) {
    #pragma unroll
    for (int mm = (1 << LG) >> 1; mm >= 4; mm >>= 1) {
        a = fmaxf(a, __shfl_xor(a, mm));
        b = fmaxf(b, __shfl_xor(b, mm));
    }
    if constexpr (LG >= 2) { a = dpp_xor2_max(a); b = dpp_xor2_max(b); }
    if constexpr (LG >= 1) { a = dpp_xor1_max(a); b = dpp_xor1_max(b); }
}

__device__ __forceinline__ bool chit(int q, const int4& c0, const int4& c1) {
    return (q == c0.x) | (q == c0.y) | (q == c0.z) | (q == c0.w) |
           (q == c1.x) | (q == c1.y) | (q == c1.z) | (q == c1.w);
}

// One CKY level with cross-barrier LDS pre-issue.
// Consume side: calv/carv hold pre-issued reads (j<P) for THIS level (issued
// last level, crossed the barrier in-flight/VGPR); the only race-unsafe terms
// (n==N-1 left child, n==0 right child -> both row N-1) come from 2 dep reads
// issued right after the barrier. j in [P,JM) are issued now (all rows final).
// Issue side: pre-issue next level's safe reads into cblv/cbrv, then a COUNTED
// lgkmcnt(2*P2) proves our row-N ds_write retired (in-order DS retirement)
// without draining the pre-issued reads -> they stay in flight across s_barrier.
template<int LG, int LG2, int JM, int JM2>
__device__ __forceinline__ void lstep(const int level, int& soff,
        const float* __restrict__ g, float2* __restrict__ chart,
        float (&rcur)[16], float (&rnxt)[16],
        float2 (&calv)[PMAX], float2 (&carv)[PMAX],
        float2 (&cblv)[PMAX], float2 (&cbrv)[PMAX],
        const int4 cc0, const int4 cc1, const int tid)
{
    const int N = level;
    const int L = LEN - level;
    constexpr int T = 1 << LG;
    constexpr int P = (JM < PMAX) ? JM : PMAX;
    const int pos = tid >> LG;
    const int sub = tid & (T - 1);
    const int soff_n = soff + L * N;

    // ---- (A) dependent reads of just-completed row N-1 (all lanes, clamped) ----
    const int rowm1 = OFFi(N - 1);
    const int pcap  = 127 - N;
    const int pdep  = (pos < pcap) ? pos : pcap;
    const float2 dlv = chart[rowm1 + pdep];
    const float2 drv = chart[rowm1 + pdep + 1];

    // ---- (A') post reads for j in [P, JM): all rows are final now ----
    float2 plv[(JM > P) ? (JM - P) : 1];
    float2 prv[(JM > P) ? (JM - P) : 1];
    if constexpr (JM > P) {
        #pragma unroll
        for (int j = P; j < JM; j++) {
            const int n = sub + j * T;
            const int m = N - 1 - n;
            const bool v = (n <= N - 1);
            const int li = OFFi(n) + pos;                       // in-bounds (pad)
            const int ri = v ? (OFFi(m) + pos + n + 1) : 0;     // clamp m<0
            plv[j - P] = chart[li];
            prv[j - P] = chart[ri];
        }
    }

    // ---- (B) global score prefetch for level+1 (in flight across barrier) ----
    if constexpr (LG2 >= 0) {
        constexpr int T2 = 1 << LG2;
        const int N2 = level + 1;
        const int L2 = L - 1;
        const int pos2 = tid >> LG2;
        const int sub2 = tid & (T2 - 1);
        if (pos2 < L2) {
            const float* __restrict__ gp = g + soff_n + pos2 * N2 + sub2;
            #pragma unroll
            for (int j = 0; j < JM2; j++)
                if (sub2 + j * T2 < N2) rnxt[j] = gp[j * T2];
        }
    }

    // ---- (C) compute ----
    float bp = -INFINITY, bc = -INFINITY;
    if (pos < L) {
        #pragma unroll
        for (int j = 0; j < P; j++) {
            const int n = sub + j * T;
            float2 lv = calv[j];
            if constexpr (JM <= PMAX) {   // n==N-1 reachable only when fully pre-issued
                const bool isdep = (n == N - 1);
                lv.x = isdep ? dlv.x : lv.x;
                lv.y = isdep ? dlv.y : lv.y;
            }
            float2 rv = carv[j];
            if (j == 0) {                 // n==0 (sub==0) right child is row N-1
                const bool r0 = (sub == 0);
                rv.x = r0 ? drv.x : rv.x;
                rv.y = r0 ? drv.y : rv.y;
            }
            const float x = (n < N) ? rcur[j] : -INFINITY;
            bp = fmaxf(bp, lv.x + rv.x + x);
            bc = fmaxf(bc, lv.y + rv.y + x);
        }
        if constexpr (JM > P) {
            #pragma unroll
            for (int j = P; j < JM; j++) {
                const int n = sub + j * T;
                const float x = (n < N) ? rcur[j] : -INFINITY;
                bp = fmaxf(bp, plv[j - P].x + prv[j - P].x + x);
                bc = fmaxf(bc, plv[j - P].y + prv[j - P].y + x);
            }
        }
    }
    redmax2<LG>(bp, bc);

    // ---- (E) write row N (bonus applied by compare: no read-modify-write) ----
    if (pos < L && sub == 0) {
        const int q = OFFi(N) + pos;
        chart[q] = make_float2(bp, bc + (chit(q, cc0, cc1) ? BONUS : 0.0f));
    }

    // ---- (F) pre-issue next level's safe reads; counted wait; barrier ----
    if constexpr (LG2 >= 0) {
        constexpr int T2 = 1 << LG2;
        constexpr int P2 = (JM2 < PMAX) ? JM2 : PMAX;
        const int pos2 = tid >> LG2;
        const int sub2 = tid & (T2 - 1);
        #pragma unroll
        for (int j = 0; j < P2; j++) {
            const int n2 = sub2 + j * T2;
            int li = OFFi(n2) + pos2;
            int ri;
            if constexpr (JM2 <= PMAX) {
                li = (n2 == N) ? 0 : li;          // row N being written -> dep later
                const int m2 = N - n2;
                ri = (n2 >= 1 && n2 <= N) ? (OFFi(m2) + pos2 + n2 + 1) : 0;
            } else {                              // n2 <= 7*T2-1 < N here
                const int m2 = N - n2;
                ri = (n2 >= 1) ? (OFFi(m2) + pos2 + n2 + 1) : 0;
            }
            cblv[j] = chart[li];
            cbrv[j] = chart[ri];
        }
        wait_lgkm<(2 * P2 <= 14) ? 2 * P2 : 14>();  // write retired; reads in flight
        bar();
    } else {
        wait_lgkm<0>();
        bar();
    }
    soff = soff_n;
}

// 4 levels at TPP=4, JM=K (levels 4K-3..4K). Parity: odd level consumes (rA,V).
template<int K>
__device__ __forceinline__ void seg4(int& soff, const float* __restrict__ g,
        float2* __restrict__ chart, float (&rA)[16], float (&rB)[16],
        float2 (&Ulv)[PMAX], float2 (&Urv)[PMAX], float2 (&Vlv)[PMAX], float2 (&Vrv)[PMAX],
        const int4 cc0, const int4 cc1, const int tid)
{
    const int l0 = 4 * K - 3;
    #pragma unroll 1
    for (int l = l0; l < l0 + 4; l += 2) {
        lstep<2,2,K,K+1>(l,   soff, g, chart, rA, rB, Vlv, Vrv, Ulv, Urv, cc0, cc1, tid);
        lstep<2,2,K,K+1>(l+1, soff, g, chart, rB, rA, Ulv, Urv, Vlv, Vrv, cc0, cc1, tid);
    }
}

__global__ __launch_bounds__(NT, 2)
void cky_fused_kernel(const float* __restrict__ scores,
                      const int* __restrict__ cpos,
                      float* __restrict__ ws)
{
    __shared__ float2 chart[NCELLS_PAD];   // .x = pred, .y = constr

    const int b   = blockIdx.x;
    const int tid = threadIdx.x;
    const float* __restrict__ g = scores + (size_t)b * TOTAL;

    float rA[16], rB[16];
    float2 Ulv[PMAX], Urv[PMAX], Vlv[PMAX], Vrv[PMAX];

    const int4 cc0 = ((const int4*)(cpos + b * NCONSTR))[0];
    const int4 cc1 = ((const int4*)(cpos + b * NCONSTR))[1];

    // prefetch scores for levels 1 and 2 (TPP=4 mapping)
    {
        const int pos = tid >> 2, sub = tid & 3;
        if (sub == 0 && pos < 127) rA[0] = g[pos];
        if (sub < 2 && pos < 126)  rB[0] = g[127 + pos * 2 + sub];
    }

    // zero chart incl. pad (garbage-lane reads must stay finite)
    #pragma unroll
    for (int k = 0; k < 17; k++) {
        const int i = tid + k * NT;
        if (i < NCELLS_PAD) chart[i] = make_float2(0.f, 0.f);
    }
    wait_lgkm<0>();
    bar();

    // ---- level 1 (terms are row0+row0+x = x; no LDS reads) ----
    {
        const int pos = tid >> 2, sub = tid & 3;
        const bool act = (sub == 0 && pos < 127);
        float bp = act ? rA[0] : -INFINITY;
        float bc = bp;
        redmax2<2>(bp, bc);
        if (act) {
            const int q = OFFi(1) + pos;
            chart[q] = make_float2(bp, bc + (chit(q, cc0, cc1) ? BONUS : 0.0f));
        }
        // pre-issue level-2 safe reads (JM2=1): j=0, n2=sub
        {
            const int n2 = sub;
            int li = OFFi(n2) + pos;
            li = (n2 == 1) ? 0 : li;                               // row 1 unsafe
            const int ri = (n2 == 1) ? (OFFi(0) + pos + 2) : 0;    // n2=1: m=0 row0
            Ulv[0] = chart[li];
            Urv[0] = chart[ri];
        }
        wait_lgkm<2>();
        bar();
    }

    int soff = 127;   // level-2 scores start

    // levels 2..4 (TPP=4, JM=1)
    lstep<2,2,1,1>(2, soff, g, chart, rB, rA, Ulv, Urv, Vlv, Vrv, cc0, cc1, tid);
    lstep<2,2,1,1>(3, soff, g, chart, rA, rB, Vlv, Vrv, Ulv, Urv, cc0, cc1, tid);
    lstep<2,2,1,2>(4, soff, g, chart, rB, rA, Ulv, Urv, Vlv, Vrv, cc0, cc1, tid);
    // levels 5..60
    seg4<2>(soff, g, chart, rA, rB, Ulv, Urv, Vlv, Vrv, cc0, cc1, tid);
    seg4<3>(soff, g, chart, rA, rB, Ulv, Urv, Vlv, Vrv, cc0, cc1, tid);
    seg4<4>(soff, g, chart, rA, rB, Ulv, Urv, Vlv, Vrv, cc0, cc1, tid);
    seg4<5>(soff, g, chart, rA, rB, Ulv, Urv, Vlv, Vrv, cc0, cc1, tid);
    seg4<6>(soff, g, chart, rA, rB, Ulv, Urv, Vlv, Vrv, cc0, cc1, tid);
    seg4<7>(soff, g, chart, rA, rB, Ulv, Urv, Vlv, Vrv, cc0, cc1, tid);
    seg4<8>(soff, g, chart, rA, rB, Ulv, Urv, Vlv, Vrv, cc0, cc1, tid);
    seg4<9>(soff, g, chart, rA, rB, Ulv, Urv, Vlv, Vrv, cc0, cc1, tid);
    seg4<10>(soff, g, chart, rA, rB, Ulv, Urv, Vlv, Vrv, cc0, cc1, tid);
    seg4<11>(soff, g, chart, rA, rB, Ulv, Urv, Vlv, Vrv, cc0, cc1, tid);
    seg4<12>(soff, g, chart, rA, rB, Ulv, Urv, Vlv, Vrv, cc0, cc1, tid);
    seg4<13>(soff, g, chart, rA, rB, Ulv, Urv, Vlv, Vrv, cc0, cc1, tid);
    seg4<14>(soff, g, chart, rA, rB, Ulv, Urv, Vlv, Vrv, cc0, cc1, tid);
    seg4<15>(soff, g, chart, rA, rB, Ulv, Urv, Vlv, Vrv, cc0, cc1, tid);
    // levels 61..63 (TPP=4, JM=16)
    lstep<2,2,16,16>(61, soff, g, chart, rA, rB, Vlv, Vrv, Ulv, Urv, cc0, cc1, tid);
    lstep<2,2,16,16>(62, soff, g, chart, rB, rA, Ulv, Urv, Vlv, Vrv, cc0, cc1, tid);
    lstep<2,3,16,8> (63, soff, g, chart, rA, rB, Vlv, Vrv, Ulv, Urv, cc0, cc1, tid);
    // levels 64..95 (TPP=8)
    lstep<3,3,8,9>  (64, soff, g, chart, rB, rA, Ulv, Urv, Vlv, Vrv, cc0, cc1, tid);
    #pragma unroll 1
    for (int l = 65; l < 72; l += 2) {
        lstep<3,3,9,10>(l,   soff, g, chart, rA, rB, Vlv, Vrv, Ulv, Urv, cc0, cc1, tid);
        lstep<3,3,9,10>(l+1, soff, g, chart, rB, rA, Ulv, Urv, Vlv, Vrv, cc0, cc1, tid);
    }
    #pragma unroll 1
    for (int l = 73; l < 80; l += 2) {
        lstep<3,3,10,11>(l,   soff, g, chart, rA, rB, Vlv, Vrv, Ulv, Urv, cc0, cc1, tid);
        lstep<3,3,10,11>(l+1, soff, g, chart, rB, rA, Ulv, Urv, Vlv, Vrv, cc0, cc1, tid);
    }
    #pragma unroll 1
    for (int l = 81; l < 88; l += 2) {
        lstep<3,3,11,12>(l,   soff, g, chart, rA, rB, Vlv, Vrv, Ulv, Urv, cc0, cc1, tid);
        lstep<3,3,11,12>(l+1, soff, g, chart, rB, rA, Ulv, Urv, Vlv, Vrv, cc0, cc1, tid);
    }
    #pragma unroll 1
    for (int l = 89; l < 94; l += 2) {
        lstep<3,3,12,12>(l,   soff, g, chart, rA, rB, Vlv, Vrv, Ulv, Urv, cc0, cc1, tid);
        lstep<3,3,12,12>(l+1, soff, g, chart, rB, rA, Ulv, Urv, Vlv, Vrv, cc0, cc1, tid);
    }
    lstep<3,4,12,6> (95, soff, g, chart, rA, rB, Vlv, Vrv, Ulv, Urv, cc0, cc1, tid);
    // levels 96..111 (TPP=16)
    lstep<4,4,6,7>  (96, soff, g, chart, rB, rA, Ulv, Urv, Vlv, Vrv, cc0, cc1, tid);
    #pragma unroll 1
    for (int l = 97; l < 110; l += 2) {
        lstep<4,4,7,7>(l,   soff, g, chart, rA, rB, Vlv, Vrv, Ulv, Urv, cc0, cc1, tid);
        lstep<4,4,7,7>(l+1, soff, g, chart, rB, rA, Ulv, Urv, Vlv, Vrv, cc0, cc1, tid);
    }
    lstep<4,5,7,4>(111, soff, g, chart, rA, rB, Vlv, Vrv, Ulv, Urv, cc0, cc1, tid);
    // levels 112..119 (TPP=32)
    lstep<5,5,4,4>(112, soff, g, chart, rB, rA, Ulv, Urv, Vlv, Vrv, cc0, cc1, tid);
    #pragma unroll 1
    for (int l = 113; l < 118; l += 2) {
        lstep<5,5,4,4>(l,   soff, g, chart, rA, rB, Vlv, Vrv, Ulv, Urv, cc0, cc1, tid);
        lstep<5,5,4,4>(l+1, soff, g, chart, rB, rA, Ulv, Urv, Vlv, Vrv, cc0, cc1, tid);
    }
    lstep<5,6,4,2>(119, soff, g, chart, rA, rB, Vlv, Vrv, Ulv, Urv, cc0, cc1, tid);
    // levels 120..127 (TPP=64)
    lstep<6,6,2,2>(120, soff, g, chart, rB, rA, Ulv, Urv, Vlv, Vrv, cc0, cc1, tid);
    #pragma unroll 1
    for (int l = 121; l < 126; l += 2) {
        lstep<6,6,2,2>(l,   soff, g, chart, rA, rB, Vlv, Vrv, Ulv, Urv, cc0, cc1, tid);
        lstep<6,6,2,2>(l+1, soff, g, chart, rB, rA, Ulv, Urv, Vlv, Vrv, cc0, cc1, tid);
    }
    lstep<6,-1,2,0>(127, soff, g, chart, rA, rB, Vlv, Vrv, Ulv, Urv, cc0, cc1, tid);

    // ---- per-batch hinge contribution ----
    if (tid == 0) {
        const float2 f = chart[OFFi(127)];
        const float pred   = f.x;
        const float constr = f.y - BONUS * NCONSTR;
        const float diff   = pred - constr;
        const float mask   = (fabsf(diff) >= 0.001f) ? 1.f : 0.f;
        const float hinge  = fmaxf(1.0f + diff, 0.f) * mask;
        atomicAdd(ws + 0, hinge);
        atomicAdd(ws + 1, mask);
    }
}

__global__ void final_kernel(const float* __restrict__ ws, float* __restrict__ out) {
    const float h = ws[0];
    const float m = ws[1];
    out[0] = (m > 0.1f) ? (h / fmaxf(m, 1.f)) : h;
}

extern "C" void kernel_launch(void* const* d_in, const int* in_sizes, int n_in,
                              void* d_out, int out_size, void* d_ws, size_t ws_size,
                              hipStream_t stream) {
    const float* scores = (const float*)d_in[0];
    const int*   cpos   = (const int*)d_in[1];
    float* out = (float*)d_out;
    float* ws  = (float*)d_ws;

    hipMemsetAsync(ws, 0, 2 * sizeof(float), stream);
    cky_fused_kernel<<<dim3(256), dim3(NT), 0, stream>>>(scores, cpos, ws);
    final_kernel<<<dim3(1), dim3(1), 0, stream>>>(ws, out);
}

// Round 8
// 141.502 us; speedup vs baseline: 1.8171x; 1.2224x over previous
//
#include <hip/hip_runtime.h>
#include <hip/hip_bf16.h>
#include <math.h>

#define LEN 128
#define NCELLS 8256          // LEN*(LEN+1)/2
#define TOTAL 349504         // sum_{l=1}^{127} (128-l)*l
#define NCONSTR 8
#define BONUS 1000.0f
#define NT 1024              // 16 waves: 2x stall overlap vs r4's 8

// Barrier WITHOUT vmcnt drain: only LDS writes must be ordered; register
// prefetch loads stay in flight across the barrier (T4 discipline).
__device__ __forceinline__ void level_barrier() {
    __builtin_amdgcn_sched_barrier(0);
    asm volatile("s_waitcnt lgkmcnt(0)\n\ts_barrier" ::: "memory");
    __builtin_amdgcn_sched_barrier(0);
}

// DPP quad_perm cross-lane max (VALU pipe, no LDS traffic).
__device__ __forceinline__ float dpp_xor1_max(float v) {
    int r = __builtin_amdgcn_update_dpp(0, __float_as_int(v), 0xB1, 0xF, 0xF, true);
    return fmaxf(v, __int_as_float(r));
}
__device__ __forceinline__ float dpp_xor2_max(float v) {
    int r = __builtin_amdgcn_update_dpp(0, __float_as_int(v), 0x4E, 0xF, 0xF, true);
    return fmaxf(v, __int_as_float(r));
}

template<int LG>
__device__ __forceinline__ void redmax2(float& a, float& b) {
    #pragma unroll
    for (int mm = (1 << LG) >> 1; mm >= 4; mm >>= 1) {
        a = fmaxf(a, __shfl_xor(a, mm));
        b = fmaxf(b, __shfl_xor(b, mm));
    }
    if constexpr (LG >= 2) { a = dpp_xor2_max(a); b = dpp_xor2_max(b); }
    if constexpr (LG >= 1) { a = dpp_xor1_max(a); b = dpp_xor1_max(b); }
}

// One CKY level (r4-verified structure). Phase 1: issue all 2*JM independent
// ds_read_b64 into register arrays; phase 2: consume. Prefetch loads level+1
// scores into rnxt (in flight across the barrier).
template<int LG, int LG2, int JM, int JM2>
__device__ __forceinline__ void lstep(const int level, int& soff,
        const float* __restrict__ g, float2* __restrict__ chart,
        float (&rcur)[16], float (&rnxt)[16], const int tid)
{
    const int N = level;
    const int L = LEN - level;
    constexpr int T = 1 << LG;
    const int pos = tid >> LG;
    const int sub = tid & (T - 1);
    const int soff_n = soff + L * N;

    // ---- issue next level's score loads (consumed after next barrier) ----
    if constexpr (LG2 >= 0) {
        constexpr int T2 = 1 << LG2;
        const int N2 = level + 1;
        const int L2 = L - 1;
        const int pos2 = tid >> LG2;
        const int sub2 = tid & (T2 - 1);
        if (pos2 < L2) {
            const float* __restrict__ gp = g + soff_n + pos2 * N2 + sub2;
            #pragma unroll
            for (int j = 0; j < JM2; j++) {
                if (sub2 + j * T2 < N2) rnxt[j] = gp[j * T2];
            }
        }
    }

    // ---- compute this level ----
    float bp = -INFINITY, bc = -INFINITY;
    if (pos < L) {
        const int jml = (N - sub + T - 1) >> LG;   // per-lane valid trip count
        float2 lv[JM], rv[JM];
        float  xs[JM];
        #pragma unroll
        for (int j = 0; j < JM; j++) {
            const int n = sub + j * T;
            const int m = level - 1 - n;
            const bool v = (j < jml);
            const int l_idx = ((n * (257 - n)) >> 1) + pos;
            int r_idx = ((m * (257 - m)) >> 1) + pos + n + 1;
            r_idx = v ? r_idx : 0;
            lv[j] = chart[l_idx];
            rv[j] = chart[r_idx];
            xs[j] = v ? rcur[j] : -INFINITY;
        }
        #pragma unroll
        for (int j = 0; j < JM; j++) {
            bp = fmaxf(bp, lv[j].x + rv[j].x + xs[j]);
            bc = fmaxf(bc, lv[j].y + rv[j].y + xs[j]);
        }
    }
    redmax2<LG>(bp, bc);
    if (pos < L && sub == 0) {
        const int q = ((level * (257 - level)) >> 1) + pos;
        float2 c = chart[q];
        c.x += bp;
        c.y += bc;
        chart[q] = c;
    }
    level_barrier();
    soff = soff_n;
}

// 8 levels at TPP=8, JM=K exactly (levels 8K-7..8K); JM2=K+1 on the last.
template<int K>
__device__ __forceinline__ void seg8(int& soff, const float* __restrict__ g,
        float2* __restrict__ chart, float (&rA)[16], float (&rB)[16], const int tid)
{
    const int l0 = 8 * K - 7;
    #pragma unroll 1
    for (int l = l0; l < l0 + 6; l += 2) {
        lstep<3, 3, K, K>(l,     soff, g, chart, rA, rB, tid);
        lstep<3, 3, K, K>(l + 1, soff, g, chart, rB, rA, tid);
    }
    lstep<3, 3, K, K>    (8 * K - 1, soff, g, chart, rA, rB, tid);
    lstep<3, 3, K, K + 1>(8 * K,     soff, g, chart, rB, rA, tid);
}

__global__ __launch_bounds__(NT)
void cky_fused_kernel(const float* __restrict__ scores,
                      const int* __restrict__ cpos,
                      float* __restrict__ ws)
{
    __shared__ float2 chart[NCELLS];   // .x = pred chart, .y = constr chart

    const int b   = blockIdx.x;
    const int tid = threadIdx.x;
    const float* __restrict__ g = scores + (size_t)b * TOTAL;

    float rA[16], rB[16];

    // ---- prefetch level 1 scores (N=1, TPP=8 mapping) ----
    {
        const int pos = tid >> 3;
        const int sub = tid & 7;
        if (pos < 127 && sub == 0) rA[0] = g[pos];
    }
    int cp = 0;
    if (tid < NCONSTR) cp = cpos[b * NCONSTR + tid];

    // ---- init both charts ----
    #pragma unroll
    for (int k = 0; k < 9; k++) {
        const int i = tid + k * NT;
        if (i < NCELLS) chart[i] = make_float2(0.f, 0.f);
    }
    level_barrier();
    if (tid < NCONSTR) chart[cp].y = BONUS;   // set (not add); duplicates benign
    level_barrier();

    int soff = 0;

    // ---- TPP=8: levels 1..56 via exact-JM segments ----
    seg8<1>(soff, g, chart, rA, rB, tid);
    seg8<2>(soff, g, chart, rA, rB, tid);
    seg8<3>(soff, g, chart, rA, rB, tid);
    seg8<4>(soff, g, chart, rA, rB, tid);
    seg8<5>(soff, g, chart, rA, rB, tid);
    seg8<6>(soff, g, chart, rA, rB, tid);
    seg8<7>(soff, g, chart, rA, rB, tid);
    // ---- TPP=8 tail: levels 57..63 (JM=8) ----
    #pragma unroll 1
    for (int l = 57; l < 63; l += 2) {
        lstep<3,3,8,8>(l,     soff, g, chart, rA, rB, tid);
        lstep<3,3,8,8>(l + 1, soff, g, chart, rB, rA, tid);
    }
    lstep<3,4,8,4>(63, soff, g, chart, rA, rB, tid);     // next TPP=16
    // ---- TPP=16: levels 64..95 ----
    lstep<4,4,4,5>(64, soff, g, chart, rB, rA, tid);
    #pragma unroll 1
    for (int l = 65; l < 79; l += 2) {                   // 65..78 (JM=5)
        lstep<4,4,5,5>(l,     soff, g, chart, rA, rB, tid);
        lstep<4,4,5,5>(l + 1, soff, g, chart, rB, rA, tid);
    }
    lstep<4,4,5,5>(79, soff, g, chart, rA, rB, tid);
    lstep<4,4,5,6>(80, soff, g, chart, rB, rA, tid);
    #pragma unroll 1
    for (int l = 81; l < 95; l += 2) {                   // 81..94 (JM=6)
        lstep<4,4,6,6>(l,     soff, g, chart, rA, rB, tid);
        lstep<4,4,6,6>(l + 1, soff, g, chart, rB, rA, tid);
    }
    lstep<4,5,6,3>(95, soff, g, chart, rA, rB, tid);     // next TPP=32
    // ---- TPP=32: levels 96..111 ----
    lstep<5,5,3,4>(96, soff, g, chart, rB, rA, tid);
    #pragma unroll 1
    for (int l = 97; l < 111; l += 2) {                  // 97..110 (JM=4)
        lstep<5,5,4,4>(l,     soff, g, chart, rA, rB, tid);
        lstep<5,5,4,4>(l + 1, soff, g, chart, rB, rA, tid);
    }
    lstep<5,6,4,2>(111, soff, g, chart, rA, rB, tid);    // next TPP=64
    // ---- TPP=64: levels 112..127 ----
    lstep<6,6,2,2>(112, soff, g, chart, rB, rA, tid);
    #pragma unroll 1
    for (int l = 113; l < 127; l += 2) {                 // 113..126
        lstep<6,6,2,2>(l,     soff, g, chart, rA, rB, tid);
        lstep<6,6,2,2>(l + 1, soff, g, chart, rB, rA, tid);
    }
    lstep<6,-1,2,0>(127, soff, g, chart, rA, rB, tid);   // root; no prefetch

    // ---- per-batch hinge contribution ----
    if (tid == 0) {
        const float2 f = chart[NCELLS - 1];
        const float pred   = f.x;
        const float constr = f.y - BONUS * NCONSTR;
        const float diff   = pred - constr;
        const float mask   = (fabsf(diff) >= 0.001f) ? 1.f : 0.f;
        const float hinge  = fmaxf(1.0f + diff, 0.f) * mask;
        atomicAdd(ws + 0, hinge);
        atomicAdd(ws + 1, mask);
    }
}

__global__ void final_kernel(const float* __restrict__ ws, float* __restrict__ out) {
    const float h = ws[0];
    const float m = ws[1];
    out[0] = (m > 0.1f) ? (h / fmaxf(m, 1.f)) : h;
}

extern "C" void kernel_launch(void* const* d_in, const int* in_sizes, int n_in,
                              void* d_out, int out_size, void* d_ws, size_t ws_size,
                              hipStream_t stream) {
    const float* scores = (const float*)d_in[0];
    const int*   cpos   = (const int*)d_in[1];
    float* out = (float*)d_out;
    float* ws  = (float*)d_ws;

    hipMemsetAsync(ws, 0, 2 * sizeof(float), stream);
    cky_fused_kernel<<<dim3(256), dim3(NT), 0, stream>>>(scores, cpos, ws);
    final_kernel<<<dim3(1), dim3(1), 0, stream>>>(ws, out);
}